// Round 20
// baseline (415.147 us; speedup 1.0000x reference)
//
#include <hip/hip_runtime.h>

typedef unsigned short u16;
typedef __attribute__((ext_vector_type(4))) unsigned short u16x4;
typedef __attribute__((ext_vector_type(8))) unsigned short u16x8;
typedef __attribute__((ext_vector_type(8))) short bf16x8;
typedef __attribute__((ext_vector_type(4))) float f32x4;

__device__ __forceinline__ u16 f2bf(float f) {
  union { float f; unsigned u; } v; v.f = f;
  unsigned r = v.u + 0x7fffu + ((v.u >> 16) & 1u);
  return (u16)(r >> 16);
}
__device__ __forceinline__ float bf2f(u16 u) {
  union { unsigned u; float f; } v; v.u = ((unsigned)u) << 16;
  return v.f;
}
__device__ __forceinline__ u16x8 pack8(f32x4 a, f32x4 b) {
  u16x8 r = { f2bf(a.x), f2bf(a.y), f2bf(a.z), f2bf(a.w),
              f2bf(b.x), f2bf(b.y), f2bf(b.z), f2bf(b.w) };
  return r;
}
// async global->LDS, 16B per lane; LDS dest = wave-uniform base + lane*16
__device__ __forceinline__ void gload16(const void* g, void* l) {
  __builtin_amdgcn_global_load_lds(
      (const __attribute__((address_space(1))) unsigned int*)g,
      (__attribute__((address_space(3))) unsigned int*)l, 16, 0, 0);
}

// ---------------- K0: weight prep (scale folded into Wq, bq) ----------------
__global__ __launch_bounds__(256) void k_prep(
    const float* __restrict__ Wq, const float* __restrict__ Wk,
    const float* __restrict__ bq, const float* __restrict__ bk,
    const float* __restrict__ Wp,
    u16* __restrict__ wqk, u16* __restrict__ wp, float* __restrict__ bqk) {
  int idx = blockIdx.x * 256 + threadIdx.x;
  if (idx < 524288) {
    int o = idx >> 9, hh = idx & 511;
    wqk[idx] = f2bf((o < 512) ? Wq[o * 512 + hh] * 0.125f : Wk[(o - 512) * 512 + hh]);
    wp[idx] = f2bf(Wp[idx]);
  }
  if (idx < 1024) bqk[idx] = (idx < 512) ? bq[idx] * 0.125f : bk[idx - 512];
}

// ---------------- K-cast: state fp32 -> stB bf16 (flat, one pass) ----------------
__global__ __launch_bounds__(256) void k_cast(
    const float* __restrict__ src, u16* __restrict__ dst) {
  size_t idx = ((size_t)blockIdx.x * 256 + threadIdx.x) * 8;
  f32x4 v0 = *(const f32x4*)&src[idx];
  f32x4 v1 = *(const f32x4*)&src[idx + 4];
  *(u16x8*)&dst[idx] = pack8(v0, v1);
}

// ---------------- K1+K2 fused: per-(i,b) qk projection + scores + softmax + head-mean ----------------
// r19 A/B: prefetch null-to-neg on both GEMMs -> stop grafting pipeline pieces.
// This round: delete the qk 268MB HBM round-trip entirely. q/k at (i,:,b) feed ONLY the
// (i,b) scores block (zero cross-block reuse), so fuse: per head n, GEMM
// [q_n|k_n](128x128) = S(128x512) x W_n^T via staged-LDS K-loop (proven structure),
// bias folded at the bf16 qs/ks write (same rounding as old qk buffer -> identical numerics),
// then the unchanged scores/softmax/head-mean code. LDS 36KB (staging overlays qs/ks).
__global__ __launch_bounds__(512) void k_qks(
    const u16* __restrict__ stB, const u16* __restrict__ wqk,
    const float* __restrict__ bqk, const unsigned char* __restrict__ mask,
    u16* __restrict__ wbuf) {
  const int i = blockIdx.x, b = blockIdx.y;
  __shared__ u16 smem[18432];  // qs[128][72] | ks[128][72] = 36864B; staging Ss[8192]+Ws[8192] overlays
  u16* qs = smem;              // 9216 u16
  u16* ks = smem + 9216;       // 9216 u16
  u16* Ss = smem;              // 8192 u16 (overlay; temporally disjoint from qs/ks use)
  u16* Ws = smem + 8192;       // 8192 u16
  const int tid = threadIdx.x, lane = tid & 63, wid = tid >> 6;  // wid 0..7
  const int l15 = lane & 15, l4 = lane >> 4;
  const int lr = lane >> 3;                       // staging row-sub 0..7
  const int lcs = ((lane & 7) ^ lr) * 8;          // swizzled source col (u16)
  const int s7 = l15 & 7;                         // read-side row&7
  // GEMM wave tile: 4M x 2N -> wave covers 32 rows x 64 cols of the 128x128 [q|k] output
  const int wm = (wid >> 1) * 32, wn2 = (wid & 1) * 64;
  float wacc[8][4];
#pragma unroll
  for (int nf = 0; nf < 8; ++nf)
#pragma unroll
    for (int r = 0; r < 4; ++r) wacc[nf][r] = 0.f;
  bool mk[8];
#pragma unroll
  for (int nf = 0; nf < 8; ++nf) mk[nf] = mask[i * 512 + b * 128 + nf * 16 + l15] != 0;
  const f32x4 fz = {0.f, 0.f, 0.f, 0.f};

  for (int h = 0; h < 8; ++h) {
    // ---- q_n|k_n GEMM: M=128(t), N=128(64 q-cols | 64 k-cols), K=512 ----
    f32x4 acc[2][4];
#pragma unroll
    for (int a = 0; a < 2; ++a)
#pragma unroll
      for (int c = 0; c < 4; ++c) acc[a][c] = fz;
    for (int ks8 = 0; ks8 < 8; ++ks8) {
      const int k0 = ks8 * 64;
      __syncthreads();  // prev kstep's readers done (h==0,ks8==0: trivially ok; later: protects qs/ks too)
#pragma unroll
      for (int j = 0; j < 2; ++j) {
        int rb = wid * 16 + j * 8;  // wave-uniform row base 0..120
        // S rows: stB[((i*128+t)*4+b)*512 + k]
        gload16(&stB[((size_t)(i * 128 + rb + lr) * 4 + b) * 512 + k0 + lcs], &Ss[rb * 64]);
        // W rows: rb<64 -> q rows (h*64+rb..), else k rows (512+h*64+rb-64..)
        const u16* wbase = (rb < 64) ? wqk + (size_t)(h * 64 + rb) * 512
                                     : wqk + (size_t)(512 + h * 64 + (rb - 64)) * 512;
        gload16(&wbase[(size_t)lr * 512 + k0 + lcs], &Ws[rb * 64]);
      }
      __syncthreads();  // vmcnt(0) drain -> staged data visible
#pragma unroll
      for (int kk = 0; kk < 64; kk += 32) {
        const int cshift = (((kk >> 3) + l4) ^ s7) * 8;
        bf16x8 af[2], bfr[4];
#pragma unroll
        for (int mf = 0; mf < 2; ++mf)
          af[mf] = *(const bf16x8*)&Ss[(wm + mf * 16 + l15) * 64 + cshift];
#pragma unroll
        for (int nf = 0; nf < 4; ++nf)
          bfr[nf] = *(const bf16x8*)&Ws[(wn2 + nf * 16 + l15) * 64 + cshift];
#pragma unroll
        for (int mf = 0; mf < 2; ++mf)
#pragma unroll
          for (int nf = 0; nf < 4; ++nf)
            acc[mf][nf] = __builtin_amdgcn_mfma_f32_16x16x32_bf16(af[mf], bfr[nf], acc[mf][nf], 0, 0, 0);
      }
    }
    // bias for this wave's 64 output cols (wave-uniform q/k branch)
    float bias[4];
#pragma unroll
    for (int nf = 0; nf < 4; ++nf)
      bias[nf] = (wn2 == 0) ? bqk[h * 64 + nf * 16 + l15]
                            : bqk[512 + h * 64 + nf * 16 + l15];
    __syncthreads();  // all waves' last-kstep MFMA LDS reads done before qs/ks overwrite staging
#pragma unroll
    for (int mf = 0; mf < 2; ++mf)
#pragma unroll
      for (int nf = 0; nf < 4; ++nf)
#pragma unroll
        for (int r = 0; r < 4; ++r) {
          int row = wm + mf * 16 + l4 * 4 + r;
          int col = wn2 + nf * 16 + l15;
          u16 v = f2bf(acc[mf][nf][r] + bias[nf]);
          if (wn2 == 0) qs[row * 72 + col] = v;
          else ks[row * 72 + (col - 64)] = v;
        }
    __syncthreads();  // qs/ks complete
    // ---- scores + softmax + head-mean (unchanged from k_scores) ----
    f32x4 sc[8];
#pragma unroll
    for (int nf = 0; nf < 8; ++nf) sc[nf] = fz;
#pragma unroll
    for (int kk = 0; kk < 64; kk += 32) {
      bf16x8 a = *(const bf16x8*)&qs[(wid * 16 + l15) * 72 + kk + l4 * 8];
#pragma unroll
      for (int nf = 0; nf < 8; ++nf) {
        bf16x8 bb = *(const bf16x8*)&ks[(nf * 16 + l15) * 72 + kk + l4 * 8];
        sc[nf] = __builtin_amdgcn_mfma_f32_16x16x32_bf16(a, bb, sc[nf], 0, 0, 0);
      }
    }
#pragma unroll
    for (int r = 0; r < 4; ++r) {
      float mx = -3e38f;
#pragma unroll
      for (int nf = 0; nf < 8; ++nf) mx = fmaxf(mx, mk[nf] ? -3e38f : sc[nf][r]);
#pragma unroll
      for (int d = 1; d < 16; d <<= 1) mx = fmaxf(mx, __shfl_xor(mx, d, 64));
      float p[8], sum = 0.f;
#pragma unroll
      for (int nf = 0; nf < 8; ++nf) {
        p[nf] = mk[nf] ? 0.f : __expf(sc[nf][r] - mx);
        sum += p[nf];
      }
#pragma unroll
      for (int d = 1; d < 16; d <<= 1) sum += __shfl_xor(sum, d, 64);
      float inv = 0.125f / sum;
#pragma unroll
      for (int nf = 0; nf < 8; ++nf) wacc[nf][r] += p[nf] * inv;
    }
  }
#pragma unroll
  for (int nf = 0; nf < 8; ++nf)
#pragma unroll
    for (int r = 0; r < 4; ++r) {
      int t = wid * 16 + l4 * 4 + r;
      wbuf[((i * 4 + b) * 128 + t) * 128 + nf * 16 + l15] = f2bf(wacc[nf][r]);
    }
}

// ---------------- K3+K4 merged: x-mix (z<4) and rel-mix (z>=4), transpose fused ----------------
__global__ __launch_bounds__(256) void k_mix(
    const u16* __restrict__ stB, const float* __restrict__ relation,
    const u16* __restrict__ wbuf, u16* __restrict__ xbuf, u16* __restrict__ relbuf) {
  const int q = blockIdx.x, b = blockIdx.y;
  const int hc = blockIdx.z & 3, path = blockIdx.z >> 2;
  __shared__ u16 smem[2 * 128 * 136];
  u16* AT = smem;              // [128][136] A^T[h'][s]
  u16* WS = smem + 128 * 136;  // [128][136] WS[.][s]; T scratch overlays this
  u16* T = WS;                 // [32][136]
  const int tid = threadIdx.x, lane = tid & 63, wid = tid >> 6;
  const int l15 = lane & 15, l4 = lane >> 4;
  const int wh = (wid >> 1) * 64, wc = (wid & 1) * 64;
  const int sr = tid >> 3, hseg = (tid & 7) * 16;  // chunk-load (32 s-rows x 128 h)
  const int th = tid >> 1, sseg = (tid & 1) * 16;  // scatter (128 h x 32 s)
#pragma unroll
  for (int ch = 0; ch < 4; ++ch) {
    const int sbase = ch * 32;
    u16x8 r0, r1;
    if (path == 0) {
      size_t gaddr = ((size_t)(q * 128 + sbase + sr) * 4 + b) * 512 + hc * 128 + hseg;
      r0 = *(const u16x8*)&stB[gaddr];
      r1 = *(const u16x8*)&stB[gaddr + 8];
    } else {
      size_t gaddr = (((size_t)(sbase + sr) * 128 + q) * 4 + b) * 512 + hc * 128 + hseg;
      f32x4 v0 = *(const f32x4*)&relation[gaddr];
      f32x4 v1 = *(const f32x4*)&relation[gaddr + 4];
      f32x4 v2 = *(const f32x4*)&relation[gaddr + 8];
      f32x4 v3 = *(const f32x4*)&relation[gaddr + 12];
      r0 = pack8(v0, v1);
      r1 = pack8(v2, v3);
    }
    __syncthreads();  // previous chunk's T readers done
    *(u16x8*)&T[sr * 136 + hseg] = r0;
    *(u16x8*)&T[sr * 136 + hseg + 8] = r1;
    __syncthreads();
    u16x8 c0, c1;
#pragma unroll
    for (int j = 0; j < 8; ++j) c0[j] = T[(sseg + j) * 136 + th];
#pragma unroll
    for (int j = 0; j < 8; ++j) c1[j] = T[(sseg + 8 + j) * 136 + th];
    *(u16x8*)&AT[th * 136 + sbase + sseg] = c0;
    *(u16x8*)&AT[th * 136 + sbase + sseg + 8] = c1;
  }
  __syncthreads();  // last chunk's T readers done before WS fill overwrites T
  const int r16 = tid >> 4, c8 = (tid & 15) * 8;
#pragma unroll
  for (int rr = 0; rr < 8; ++rr) {
    int row = rr * 16 + r16;
    const u16* src = (path == 0) ? &wbuf[((q * 4 + b) * 128 + row) * 128 + c8]
                                 : &wbuf[((row * 4 + b) * 128 + q) * 128 + c8];
    *(u16x8*)&WS[row * 136 + c8] = *(const u16x8*)src;
  }
  __syncthreads();
  const f32x4 fz = {0.f, 0.f, 0.f, 0.f};
  f32x4 acc[4][4];
#pragma unroll
  for (int a = 0; a < 4; ++a)
#pragma unroll
    for (int c = 0; c < 4; ++c) acc[a][c] = fz;
#pragma unroll
  for (int kk = 0; kk < 128; kk += 32) {
    bf16x8 af[4], bfr[4];
#pragma unroll
    for (int mf = 0; mf < 4; ++mf)
      af[mf] = *(const bf16x8*)&AT[(wh + mf * 16 + l15) * 136 + kk + l4 * 8];
#pragma unroll
    for (int nf = 0; nf < 4; ++nf)
      bfr[nf] = *(const bf16x8*)&WS[(wc + nf * 16 + l15) * 136 + kk + l4 * 8];
#pragma unroll
    for (int mf = 0; mf < 4; ++mf)
#pragma unroll
      for (int nf = 0; nf < 4; ++nf)
        acc[mf][nf] = __builtin_amdgcn_mfma_f32_16x16x32_bf16(af[mf], bfr[nf], acc[mf][nf], 0, 0, 0);
  }
  __syncthreads();
  u16* Cs = smem;  // [out][h] 128x136
#pragma unroll
  for (int mf = 0; mf < 4; ++mf)
#pragma unroll
    for (int nf = 0; nf < 4; ++nf) {
      int h0 = wh + mf * 16 + l4 * 4;
      int oc = wc + nf * 16 + l15;
      u16x4 pk = { f2bf(acc[mf][nf][0]), f2bf(acc[mf][nf][1]),
                   f2bf(acc[mf][nf][2]), f2bf(acc[mf][nf][3]) };
      *(u16x4*)&Cs[oc * 136 + h0] = pk;
    }
  __syncthreads();
#pragma unroll
  for (int rr = 0; rr < 8; ++rr) {
    int o = rr * 16 + r16;
    u16x8 v = *(const u16x8*)&Cs[o * 136 + c8];
    if (path == 0)
      *(u16x8*)&xbuf[((q * 128 + o) * 4 + b) * 512 + hc * 128 + c8] = v;
    else
      *(u16x8*)&relbuf[((o * 128 + q) * 4 + b) * 512 + hc * 128 + c8] = v;
  }
}

// ---------------- K5a: out-proj GEMM (M=65536,N=512,K=1024) + bias + relu -> yb bf16 ----------------
// 2-barrier form (measured-good).
__global__ __launch_bounds__(256) void k_proj(
    const u16* __restrict__ xbuf, const u16* __restrict__ relbuf,
    const u16* __restrict__ wp, const float* __restrict__ bp,
    u16* __restrict__ yb) {
  const int flat = blockIdx.x;
  const int xcd = flat & 7, local = flat >> 3;          // local 0..255
  const int m0 = (xcd * 64 + (local >> 2)) * 128;
  const int n0 = (local & 3) * 128;
  __shared__ u16 smem[17408];
  u16* As = smem;
  u16* Bs = smem + 8192;
  const int tid = threadIdx.x, lane = tid & 63, wid = tid >> 6;
  const int l15 = lane & 15, l4 = lane >> 4;
  const int wm = (wid >> 1) * 64, wn = (wid & 1) * 64;
  const int lr = lane >> 3;
  const int lcs = ((lane & 7) ^ lr) * 8;
  const int s7 = l15 & 7;
  const f32x4 fz = {0.f, 0.f, 0.f, 0.f};
  f32x4 acc[4][4];
#pragma unroll
  for (int a = 0; a < 4; ++a)
#pragma unroll
    for (int c = 0; c < 4; ++c) acc[a][c] = fz;
  for (int k0 = 0; k0 < 1024; k0 += 64) {
    if (k0) __syncthreads();
    const u16* abase = (k0 < 512) ? xbuf + k0 : relbuf + (k0 - 512);
#pragma unroll
    for (int j = 0; j < 4; ++j) {
      int rb = wid * 32 + j * 8;
      gload16(&abase[(size_t)(m0 + rb + lr) * 512 + lcs], &As[rb * 64]);
      gload16(&wp[(size_t)(n0 + rb + lr) * 1024 + k0 + lcs], &Bs[rb * 64]);
    }
    __syncthreads();
#pragma unroll
    for (int kk = 0; kk < 64; kk += 32) {
      const int cshift = (((kk >> 3) + l4) ^ s7) * 8;
      bf16x8 af[4], bfr[4];
#pragma unroll
      for (int mf = 0; mf < 4; ++mf)
        af[mf] = *(const bf16x8*)&As[(wm + mf * 16 + l15) * 64 + cshift];
#pragma unroll
      for (int nf = 0; nf < 4; ++nf)
        bfr[nf] = *(const bf16x8*)&Bs[(wn + nf * 16 + l15) * 64 + cshift];
#pragma unroll
      for (int mf = 0; mf < 4; ++mf)
#pragma unroll
        for (int nf = 0; nf < 4; ++nf)
          acc[mf][nf] = __builtin_amdgcn_mfma_f32_16x16x32_bf16(af[mf], bfr[nf], acc[mf][nf], 0, 0, 0);
    }
  }
  float bias[4];
#pragma unroll
  for (int nf = 0; nf < 4; ++nf) bias[nf] = bp[n0 + wn + nf * 16 + l15];
  __syncthreads();
  u16* Cs = smem;  // [128][136]
#pragma unroll
  for (int mf = 0; mf < 4; ++mf)
#pragma unroll
    for (int nf = 0; nf < 4; ++nf)
#pragma unroll
      for (int r = 0; r < 4; ++r)
        Cs[(wm + mf * 16 + l4 * 4 + r) * 136 + wn + nf * 16 + l15] =
            f2bf(fmaxf(acc[mf][nf][r] + bias[nf], 0.f));
  __syncthreads();
#pragma unroll
  for (int rr = 0; rr < 8; ++rr) {
    int row = rr * 16 + (tid >> 4), c8 = (tid & 15) * 8;
    *(u16x8*)&yb[(size_t)(m0 + row) * 512 + n0 + c8] = *(const u16x8*)&Cs[row * 136 + c8];
  }
}

// ---------------- K5b: residual + LayerNorm (memory-bound row pass) ----------------
__global__ __launch_bounds__(256) void k_ln(
    const u16* __restrict__ yb, const u16* __restrict__ stB,
    const float* __restrict__ gamma, const float* __restrict__ beta,
    float* __restrict__ out) {
  const int tid = threadIdx.x, lane = tid & 63, wid = tid >> 6;
  f32x4 g0 = *(const f32x4*)&gamma[lane * 8];
  f32x4 g1 = *(const f32x4*)&gamma[lane * 8 + 4];
  f32x4 be0 = *(const f32x4*)&beta[lane * 8];
  f32x4 be1 = *(const f32x4*)&beta[lane * 8 + 4];
  for (int row = blockIdx.x * 4 + wid; row < 65536; row += gridDim.x * 4) {
    size_t gbase = (size_t)row * 512 + lane * 8;
    u16x8 yv = *(const u16x8*)&yb[gbase];
    u16x8 sv = *(const u16x8*)&stB[gbase];
    float y[8];
#pragma unroll
    for (int j = 0; j < 8; ++j) y[j] = bf2f(yv[j]) + bf2f(sv[j]);
    float sum = 0.f, sq = 0.f;
#pragma unroll
    for (int j = 0; j < 8; ++j) { sum += y[j]; sq += y[j] * y[j]; }
#pragma unroll
    for (int d = 1; d < 64; d <<= 1) { sum += __shfl_xor(sum, d, 64); sq += __shfl_xor(sq, d, 64); }
    float mu = sum * (1.f / 512.f);
    float var = sq * (1.f / 512.f) - mu * mu;
    float rs = rsqrtf(var + 1e-5f);
    f32x4 o0, o1;
#pragma unroll
    for (int j = 0; j < 4; ++j) o0[j] = g0[j] * (y[j] - mu) * rs + be0[j];
#pragma unroll
    for (int j = 0; j < 4; ++j) o1[j] = g1[j] * (y[4 + j] - mu) * rs + be1[j];
    *(f32x4*)&out[gbase] = o0;
    *(f32x4*)&out[gbase + 4] = o1;
  }
}

extern "C" void kernel_launch(void* const* d_in, const int* in_sizes, int n_in,
                              void* d_out, int out_size, void* d_ws, size_t ws_size,
                              hipStream_t stream) {
  const float* state = (const float*)d_in[0];
  const float* relation = (const float*)d_in[1];
  const unsigned char* mask = (const unsigned char*)d_in[2];
  const float* Wq = (const float*)d_in[4];
  const float* bq = (const float*)d_in[5];
  const float* Wk = (const float*)d_in[6];
  const float* bk = (const float*)d_in[7];
  const float* Wp = (const float*)d_in[8];
  const float* bp = (const float*)d_in[9];
  const float* gamma = (const float*)d_in[10];
  const float* beta = (const float*)d_in[11];
  float* out = (float*)d_out;
  char* ws = (char*)d_ws;

  // workspace layout (bytes); qk buffer eliminated (k_qks fusion); xbuf/relbuf
  // use its region; stB read by k_qks, k_mix, k_ln.
  u16* xbuf   = (u16*)(ws);                    //  67,108,864
  u16* relbuf = (u16*)(ws + 67108864);         //  67,108,864
  u16* yb     = (u16*)(ws + 134217728);        //  67,108,864
  u16* stB    = (u16*)(ws + 201326592);        //  67,108,864
  u16* wbuf   = (u16*)(ws + 268435456);        //  16,777,216
  u16* wqk    = (u16*)(ws + 285212672);        //   1,048,576
  u16* wp     = (u16*)(ws + 286261248);        //   1,048,576
  float* bqk  = (float*)(ws + 287309824);      //       4,096

  k_prep<<<2048, 256, 0, stream>>>(Wq, Wk, bq, bk, Wp, wqk, wp, bqk);
  k_cast<<<16384, 256, 0, stream>>>(state, stB);
  k_qks<<<dim3(128, 4), 512, 0, stream>>>(stB, wqk, bqk, mask, wbuf);
  k_mix<<<dim3(128, 4, 8), 256, 0, stream>>>(stB, relation, wbuf, xbuf, relbuf);
  k_proj<<<2048, 256, 0, stream>>>(xbuf, relbuf, wp, bp, yb);
  k_ln<<<2048, 256, 0, stream>>>(yb, stB, gamma, beta, out);
}

// Round 21
// 376.844 us; speedup vs baseline: 1.1016x; 1.1016x over previous
//
#include <hip/hip_runtime.h>

typedef unsigned short u16;
typedef __attribute__((ext_vector_type(4))) unsigned short u16x4;
typedef __attribute__((ext_vector_type(8))) unsigned short u16x8;
typedef __attribute__((ext_vector_type(8))) short bf16x8;
typedef __attribute__((ext_vector_type(4))) float f32x4;

__device__ __forceinline__ u16 f2bf(float f) {
  union { float f; unsigned u; } v; v.f = f;
  unsigned r = v.u + 0x7fffu + ((v.u >> 16) & 1u);
  return (u16)(r >> 16);
}
__device__ __forceinline__ float bf2f(u16 u) {
  union { unsigned u; float f; } v; v.u = ((unsigned)u) << 16;
  return v.f;
}
__device__ __forceinline__ u16x8 pack8(f32x4 a, f32x4 b) {
  u16x8 r = { f2bf(a.x), f2bf(a.y), f2bf(a.z), f2bf(a.w),
              f2bf(b.x), f2bf(b.y), f2bf(b.z), f2bf(b.w) };
  return r;
}
// async global->LDS, 16B per lane; LDS dest = wave-uniform base + lane*16
__device__ __forceinline__ void gload16(const void* g, void* l) {
  __builtin_amdgcn_global_load_lds(
      (const __attribute__((address_space(1))) unsigned int*)g,
      (__attribute__((address_space(3))) unsigned int*)l, 16, 0, 0);
}

// ---------------- K0: weight prep (scale folded into Wq, bq) ----------------
__global__ __launch_bounds__(256) void k_prep(
    const float* __restrict__ Wq, const float* __restrict__ Wk,
    const float* __restrict__ bq, const float* __restrict__ bk,
    const float* __restrict__ Wp,
    u16* __restrict__ wqk, u16* __restrict__ wp, float* __restrict__ bqk) {
  int idx = blockIdx.x * 256 + threadIdx.x;
  if (idx < 524288) {
    int o = idx >> 9, hh = idx & 511;
    wqk[idx] = f2bf((o < 512) ? Wq[o * 512 + hh] * 0.125f : Wk[(o - 512) * 512 + hh]);
    wp[idx] = f2bf(Wp[idx]);
  }
  if (idx < 1024) bqk[idx] = (idx < 512) ? bq[idx] * 0.125f : bk[idx - 512];
}

// ---------------- K-cast: state fp32 -> stB bf16 (flat, one pass) ----------------
__global__ __launch_bounds__(256) void k_cast(
    const float* __restrict__ src, u16* __restrict__ dst) {
  size_t idx = ((size_t)blockIdx.x * 256 + threadIdx.x) * 8;
  f32x4 v0 = *(const f32x4*)&src[idx];
  f32x4 v1 = *(const f32x4*)&src[idx + 4];
  *(u16x8*)&dst[idx] = pack8(v0, v1);
}

// ---------------- K1: q,k projection GEMM (M=65536, N=1024, K=512), bf16 in/out ----------------
// r17 measured-optimum config (99us, 28% MfmaUtil, 26% Occ). 128x128 tile, 2-barrier
// K-loop, XCD-chunked swizzle (FETCH 525->45MB) + both-sides XOR bank swizzle
// (conflicts 49x down). Structural alternatives all measured worse: 128x256 tile
// (r16: occupancy collapse), dbuf prefetch (r19: null-to-neg), proj+scores fusion
// (r20: barrier serialization, 187us).
__global__ __launch_bounds__(256) void k_qkproj(
    const u16* __restrict__ stB, const u16* __restrict__ wqk,
    const float* __restrict__ bqk, u16* __restrict__ qk) {
  const int flat = blockIdx.x;
  const int xcd = flat & 7, local = flat >> 3;          // local 0..511
  const int m0 = (xcd * 64 + (local >> 3)) * 128;       // 512 m-tiles, 64 per XCD
  const int n0 = (local & 7) * 128;                     // 8 n-tiles
  __shared__ u16 smem[17408];  // As[128*64] | Bs[128*64]; epilogue Cs[128][136] overlays
  u16* As = smem;
  u16* Bs = smem + 8192;
  const int tid = threadIdx.x, lane = tid & 63, wid = tid >> 6;
  const int l15 = lane & 15, l4 = lane >> 4;
  const int wm = (wid >> 1) * 64, wn = (wid & 1) * 64;
  const int lr = lane >> 3;                       // staging row-sub 0..7
  const int lcs = ((lane & 7) ^ lr) * 8;          // swizzled source col (u16)
  const int s7 = l15 & 7;                         // read-side row&7
  const f32x4 fz = {0.f, 0.f, 0.f, 0.f};
  f32x4 acc[4][4];
#pragma unroll
  for (int a = 0; a < 4; ++a)
#pragma unroll
    for (int c = 0; c < 4; ++c) acc[a][c] = fz;
  for (int k0 = 0; k0 < 512; k0 += 64) {
    if (k0) __syncthreads();
#pragma unroll
    for (int j = 0; j < 4; ++j) {
      int rb = wid * 32 + j * 8;  // wave-uniform row base
      gload16(&stB[(size_t)(m0 + rb + lr) * 512 + k0 + lcs], &As[rb * 64]);
      gload16(&wqk[(size_t)(n0 + rb + lr) * 512 + k0 + lcs], &Bs[rb * 64]);
    }
    __syncthreads();  // drains vmcnt(0) -> staged data visible
#pragma unroll
    for (int kk = 0; kk < 64; kk += 32) {
      const int cshift = (((kk >> 3) + l4) ^ s7) * 8;  // swizzled read col (u16)
      bf16x8 af[4], bfr[4];
#pragma unroll
      for (int mf = 0; mf < 4; ++mf)
        af[mf] = *(const bf16x8*)&As[(wm + mf * 16 + l15) * 64 + cshift];
#pragma unroll
      for (int nf = 0; nf < 4; ++nf)
        bfr[nf] = *(const bf16x8*)&Bs[(wn + nf * 16 + l15) * 64 + cshift];
#pragma unroll
      for (int mf = 0; mf < 4; ++mf)
#pragma unroll
        for (int nf = 0; nf < 4; ++nf)
          acc[mf][nf] = __builtin_amdgcn_mfma_f32_16x16x32_bf16(af[mf], bfr[nf], acc[mf][nf], 0, 0, 0);
    }
  }
  float bias[4];
#pragma unroll
  for (int nf = 0; nf < 4; ++nf) bias[nf] = bqk[n0 + wn + nf * 16 + l15];
  __syncthreads();
  u16* Cs = smem;  // [128][136]
#pragma unroll
  for (int mf = 0; mf < 4; ++mf)
#pragma unroll
    for (int nf = 0; nf < 4; ++nf)
#pragma unroll
      for (int r = 0; r < 4; ++r)
        Cs[(wm + mf * 16 + l4 * 4 + r) * 136 + wn + nf * 16 + l15] =
            f2bf(acc[mf][nf][r] + bias[nf]);
  __syncthreads();
#pragma unroll
  for (int rr = 0; rr < 8; ++rr) {
    int row = rr * 16 + (tid >> 4), c8 = (tid & 15) * 8;
    *(u16x8*)&qk[(size_t)(m0 + row) * 1024 + n0 + c8] = *(const u16x8*)&Cs[row * 136 + c8];
  }
}

// ---------------- K2: per-(i,b) scores -> softmax -> head-mean -> w (bf16) ----------------
__global__ __launch_bounds__(512) void k_scores(
    const u16* __restrict__ qk, const unsigned char* __restrict__ mask,
    u16* __restrict__ wbuf) {
  const int i = blockIdx.x, b = blockIdx.y;
  __shared__ u16 smem[2 * 128 * 72];
  u16* qs = smem;
  u16* ks = smem + 128 * 72;
  const int tid = threadIdx.x, lane = tid & 63, wid = tid >> 6;  // wid 0..7
  const int l15 = lane & 15, l4 = lane >> 4;
  float wacc[8][4];
#pragma unroll
  for (int nf = 0; nf < 8; ++nf)
#pragma unroll
    for (int r = 0; r < 4; ++r) wacc[nf][r] = 0.f;
  bool mk[8];
#pragma unroll
  for (int nf = 0; nf < 8; ++nf) mk[nf] = mask[i * 512 + b * 128 + nf * 16 + l15] != 0;
  const int arow = tid >> 3, acol = (tid & 7) * 8;  // arow 0..63
  const f32x4 fz = {0.f, 0.f, 0.f, 0.f};
  for (int h = 0; h < 8; ++h) {
    __syncthreads();
#pragma unroll
    for (int rr = 0; rr < 2; ++rr) {
      int row = rr * 64 + arow;
      int base = ((i * 128 + row) * 4 + b) * 1024 + h * 64 + acol;
      *(u16x8*)&qs[row * 72 + acol] = *(const u16x8*)&qk[base];
      *(u16x8*)&ks[row * 72 + acol] = *(const u16x8*)&qk[base + 512];
    }
    __syncthreads();
    f32x4 sc[8];
#pragma unroll
    for (int nf = 0; nf < 8; ++nf) sc[nf] = fz;
#pragma unroll
    for (int kk = 0; kk < 64; kk += 32) {
      bf16x8 a = *(const bf16x8*)&qs[(wid * 16 + l15) * 72 + kk + l4 * 8];
#pragma unroll
      for (int nf = 0; nf < 8; ++nf) {
        bf16x8 bb = *(const bf16x8*)&ks[(nf * 16 + l15) * 72 + kk + l4 * 8];
        sc[nf] = __builtin_amdgcn_mfma_f32_16x16x32_bf16(a, bb, sc[nf], 0, 0, 0);
      }
    }
#pragma unroll
    for (int r = 0; r < 4; ++r) {
      float mx = -3e38f;
#pragma unroll
      for (int nf = 0; nf < 8; ++nf) mx = fmaxf(mx, mk[nf] ? -3e38f : sc[nf][r]);
#pragma unroll
      for (int d = 1; d < 16; d <<= 1) mx = fmaxf(mx, __shfl_xor(mx, d, 64));
      float p[8], sum = 0.f;
#pragma unroll
      for (int nf = 0; nf < 8; ++nf) {
        p[nf] = mk[nf] ? 0.f : __expf(sc[nf][r] - mx);
        sum += p[nf];
      }
#pragma unroll
      for (int d = 1; d < 16; d <<= 1) sum += __shfl_xor(sum, d, 64);
      float inv = 0.125f / sum;
#pragma unroll
      for (int nf = 0; nf < 8; ++nf) wacc[nf][r] += p[nf] * inv;
    }
  }
#pragma unroll
  for (int nf = 0; nf < 8; ++nf)
#pragma unroll
    for (int r = 0; r < 4; ++r) {
      int t = wid * 16 + l4 * 4 + r;
      wbuf[((i * 4 + b) * 128 + t) * 128 + nf * 16 + l15] = f2bf(wacc[nf][r]);
    }
}

// ---------------- K3+K4 merged: x-mix (z<4) and rel-mix (z>=4), transpose fused ----------------
__global__ __launch_bounds__(256) void k_mix(
    const u16* __restrict__ stB, const float* __restrict__ relation,
    const u16* __restrict__ wbuf, u16* __restrict__ xbuf, u16* __restrict__ relbuf) {
  const int q = blockIdx.x, b = blockIdx.y;
  const int hc = blockIdx.z & 3, path = blockIdx.z >> 2;
  __shared__ u16 smem[2 * 128 * 136];
  u16* AT = smem;              // [128][136] A^T[h'][s]
  u16* WS = smem + 128 * 136;  // [128][136] WS[.][s]; T scratch overlays this
  u16* T = WS;                 // [32][136]
  const int tid = threadIdx.x, lane = tid & 63, wid = tid >> 6;
  const int l15 = lane & 15, l4 = lane >> 4;
  const int wh = (wid >> 1) * 64, wc = (wid & 1) * 64;
  const int sr = tid >> 3, hseg = (tid & 7) * 16;  // chunk-load (32 s-rows x 128 h)
  const int th = tid >> 1, sseg = (tid & 1) * 16;  // scatter (128 h x 32 s)
#pragma unroll
  for (int ch = 0; ch < 4; ++ch) {
    const int sbase = ch * 32;
    u16x8 r0, r1;
    if (path == 0) {
      size_t gaddr = ((size_t)(q * 128 + sbase + sr) * 4 + b) * 512 + hc * 128 + hseg;
      r0 = *(const u16x8*)&stB[gaddr];
      r1 = *(const u16x8*)&stB[gaddr + 8];
    } else {
      size_t gaddr = (((size_t)(sbase + sr) * 128 + q) * 4 + b) * 512 + hc * 128 + hseg;
      f32x4 v0 = *(const f32x4*)&relation[gaddr];
      f32x4 v1 = *(const f32x4*)&relation[gaddr + 4];
      f32x4 v2 = *(const f32x4*)&relation[gaddr + 8];
      f32x4 v3 = *(const f32x4*)&relation[gaddr + 12];
      r0 = pack8(v0, v1);
      r1 = pack8(v2, v3);
    }
    __syncthreads();  // previous chunk's T readers done
    *(u16x8*)&T[sr * 136 + hseg] = r0;
    *(u16x8*)&T[sr * 136 + hseg + 8] = r1;
    __syncthreads();
    u16x8 c0, c1;
#pragma unroll
    for (int j = 0; j < 8; ++j) c0[j] = T[(sseg + j) * 136 + th];
#pragma unroll
    for (int j = 0; j < 8; ++j) c1[j] = T[(sseg + 8 + j) * 136 + th];
    *(u16x8*)&AT[th * 136 + sbase + sseg] = c0;
    *(u16x8*)&AT[th * 136 + sbase + sseg + 8] = c1;
  }
  __syncthreads();  // last chunk's T readers done before WS fill overwrites T
  const int r16 = tid >> 4, c8 = (tid & 15) * 8;
#pragma unroll
  for (int rr = 0; rr < 8; ++rr) {
    int row = rr * 16 + r16;
    const u16* src = (path == 0) ? &wbuf[((q * 4 + b) * 128 + row) * 128 + c8]
                                 : &wbuf[((row * 4 + b) * 128 + q) * 128 + c8];
    *(u16x8*)&WS[row * 136 + c8] = *(const u16x8*)src;
  }
  __syncthreads();
  const f32x4 fz = {0.f, 0.f, 0.f, 0.f};
  f32x4 acc[4][4];
#pragma unroll
  for (int a = 0; a < 4; ++a)
#pragma unroll
    for (int c = 0; c < 4; ++c) acc[a][c] = fz;
#pragma unroll
  for (int kk = 0; kk < 128; kk += 32) {
    bf16x8 af[4], bfr[4];
#pragma unroll
    for (int mf = 0; mf < 4; ++mf)
      af[mf] = *(const bf16x8*)&AT[(wh + mf * 16 + l15) * 136 + kk + l4 * 8];
#pragma unroll
    for (int nf = 0; nf < 4; ++nf)
      bfr[nf] = *(const bf16x8*)&WS[(wc + nf * 16 + l15) * 136 + kk + l4 * 8];
#pragma unroll
    for (int mf = 0; mf < 4; ++mf)
#pragma unroll
      for (int nf = 0; nf < 4; ++nf)
        acc[mf][nf] = __builtin_amdgcn_mfma_f32_16x16x32_bf16(af[mf], bfr[nf], acc[mf][nf], 0, 0, 0);
  }
  __syncthreads();
  u16* Cs = smem;  // [out][h] 128x136
#pragma unroll
  for (int mf = 0; mf < 4; ++mf)
#pragma unroll
    for (int nf = 0; nf < 4; ++nf) {
      int h0 = wh + mf * 16 + l4 * 4;
      int oc = wc + nf * 16 + l15;
      u16x4 pk = { f2bf(acc[mf][nf][0]), f2bf(acc[mf][nf][1]),
                   f2bf(acc[mf][nf][2]), f2bf(acc[mf][nf][3]) };
      *(u16x4*)&Cs[oc * 136 + h0] = pk;
    }
  __syncthreads();
#pragma unroll
  for (int rr = 0; rr < 8; ++rr) {
    int o = rr * 16 + r16;
    u16x8 v = *(const u16x8*)&Cs[o * 136 + c8];
    if (path == 0)
      *(u16x8*)&xbuf[((q * 128 + o) * 4 + b) * 512 + hc * 128 + c8] = v;
    else
      *(u16x8*)&relbuf[((o * 128 + q) * 4 + b) * 512 + hc * 128 + c8] = v;
  }
}

// ---------------- K5a: out-proj GEMM (M=65536,N=512,K=1024) + bias + relu -> yb bf16 ----------------
// 2-barrier form (measured-good).
__global__ __launch_bounds__(256) void k_proj(
    const u16* __restrict__ xbuf, const u16* __restrict__ relbuf,
    const u16* __restrict__ wp, const float* __restrict__ bp,
    u16* __restrict__ yb) {
  const int flat = blockIdx.x;
  const int xcd = flat & 7, local = flat >> 3;          // local 0..255
  const int m0 = (xcd * 64 + (local >> 2)) * 128;
  const int n0 = (local & 3) * 128;
  __shared__ u16 smem[17408];
  u16* As = smem;
  u16* Bs = smem + 8192;
  const int tid = threadIdx.x, lane = tid & 63, wid = tid >> 6;
  const int l15 = lane & 15, l4 = lane >> 4;
  const int wm = (wid >> 1) * 64, wn = (wid & 1) * 64;
  const int lr = lane >> 3;
  const int lcs = ((lane & 7) ^ lr) * 8;
  const int s7 = l15 & 7;
  const f32x4 fz = {0.f, 0.f, 0.f, 0.f};
  f32x4 acc[4][4];
#pragma unroll
  for (int a = 0; a < 4; ++a)
#pragma unroll
    for (int c = 0; c < 4; ++c) acc[a][c] = fz;
  for (int k0 = 0; k0 < 1024; k0 += 64) {
    if (k0) __syncthreads();
    const u16* abase = (k0 < 512) ? xbuf + k0 : relbuf + (k0 - 512);
#pragma unroll
    for (int j = 0; j < 4; ++j) {
      int rb = wid * 32 + j * 8;
      gload16(&abase[(size_t)(m0 + rb + lr) * 512 + lcs], &As[rb * 64]);
      gload16(&wp[(size_t)(n0 + rb + lr) * 1024 + k0 + lcs], &Bs[rb * 64]);
    }
    __syncthreads();
#pragma unroll
    for (int kk = 0; kk < 64; kk += 32) {
      const int cshift = (((kk >> 3) + l4) ^ s7) * 8;
      bf16x8 af[4], bfr[4];
#pragma unroll
      for (int mf = 0; mf < 4; ++mf)
        af[mf] = *(const bf16x8*)&As[(wm + mf * 16 + l15) * 64 + cshift];
#pragma unroll
      for (int nf = 0; nf < 4; ++nf)
        bfr[nf] = *(const bf16x8*)&Bs[(wn + nf * 16 + l15) * 64 + cshift];
#pragma unroll
      for (int mf = 0; mf < 4; ++mf)
#pragma unroll
        for (int nf = 0; nf < 4; ++nf)
          acc[mf][nf] = __builtin_amdgcn_mfma_f32_16x16x32_bf16(af[mf], bfr[nf], acc[mf][nf], 0, 0, 0);
    }
  }
  float bias[4];
#pragma unroll
  for (int nf = 0; nf < 4; ++nf) bias[nf] = bp[n0 + wn + nf * 16 + l15];
  __syncthreads();
  u16* Cs = smem;  // [128][136]
#pragma unroll
  for (int mf = 0; mf < 4; ++mf)
#pragma unroll
    for (int nf = 0; nf < 4; ++nf)
#pragma unroll
      for (int r = 0; r < 4; ++r)
        Cs[(wm + mf * 16 + l4 * 4 + r) * 136 + wn + nf * 16 + l15] =
            f2bf(fmaxf(acc[mf][nf][r] + bias[nf], 0.f));
  __syncthreads();
#pragma unroll
  for (int rr = 0; rr < 8; ++rr) {
    int row = rr * 16 + (tid >> 4), c8 = (tid & 15) * 8;
    *(u16x8*)&yb[(size_t)(m0 + row) * 512 + n0 + c8] = *(const u16x8*)&Cs[row * 136 + c8];
  }
}

// ---------------- K5b: residual + LayerNorm (memory-bound row pass) ----------------
__global__ __launch_bounds__(256) void k_ln(
    const u16* __restrict__ yb, const u16* __restrict__ stB,
    const float* __restrict__ gamma, const float* __restrict__ beta,
    float* __restrict__ out) {
  const int tid = threadIdx.x, lane = tid & 63, wid = tid >> 6;
  f32x4 g0 = *(const f32x4*)&gamma[lane * 8];
  f32x4 g1 = *(const f32x4*)&gamma[lane * 8 + 4];
  f32x4 be0 = *(const f32x4*)&beta[lane * 8];
  f32x4 be1 = *(const f32x4*)&beta[lane * 8 + 4];
  for (int row = blockIdx.x * 4 + wid; row < 65536; row += gridDim.x * 4) {
    size_t gbase = (size_t)row * 512 + lane * 8;
    u16x8 yv = *(const u16x8*)&yb[gbase];
    u16x8 sv = *(const u16x8*)&stB[gbase];
    float y[8];
#pragma unroll
    for (int j = 0; j < 8; ++j) y[j] = bf2f(yv[j]) + bf2f(sv[j]);
    float sum = 0.f, sq = 0.f;
#pragma unroll
    for (int j = 0; j < 8; ++j) { sum += y[j]; sq += y[j] * y[j]; }
#pragma unroll
    for (int d = 1; d < 64; d <<= 1) { sum += __shfl_xor(sum, d, 64); sq += __shfl_xor(sq, d, 64); }
    float mu = sum * (1.f / 512.f);
    float var = sq * (1.f / 512.f) - mu * mu;
    float rs = rsqrtf(var + 1e-5f);
    f32x4 o0, o1;
#pragma unroll
    for (int j = 0; j < 4; ++j) o0[j] = g0[j] * (y[j] - mu) * rs + be0[j];
#pragma unroll
    for (int j = 0; j < 4; ++j) o1[j] = g1[j] * (y[4 + j] - mu) * rs + be1[j];
    *(f32x4*)&out[gbase] = o0;
    *(f32x4*)&out[gbase + 4] = o1;
  }
}

extern "C" void kernel_launch(void* const* d_in, const int* in_sizes, int n_in,
                              void* d_out, int out_size, void* d_ws, size_t ws_size,
                              hipStream_t stream) {
  const float* state = (const float*)d_in[0];
  const float* relation = (const float*)d_in[1];
  const unsigned char* mask = (const unsigned char*)d_in[2];
  const float* Wq = (const float*)d_in[4];
  const float* bq = (const float*)d_in[5];
  const float* Wk = (const float*)d_in[6];
  const float* bk = (const float*)d_in[7];
  const float* Wp = (const float*)d_in[8];
  const float* bp = (const float*)d_in[9];
  const float* gamma = (const float*)d_in[10];
  const float* beta = (const float*)d_in[11];
  float* out = (float*)d_out;
  char* ws = (char*)d_ws;

  // workspace layout (bytes); aliases (lifetimes disjoint):
  //   xbuf/relbuf alias qk (dead after k_scores)
  //   stB read by k_qkproj, k_mix, k_ln — nothing overwrites its region
  u16* qk     = (u16*)(ws);                    // 134,217,728
  u16* xbuf   = (u16*)(ws);                    //  67,108,864 (alias qk lower half)
  u16* relbuf = (u16*)(ws + 67108864);         //  67,108,864 (alias qk upper half)
  u16* yb     = (u16*)(ws + 134217728);        //  67,108,864
  u16* stB    = (u16*)(ws + 201326592);        //  67,108,864
  u16* wbuf   = (u16*)(ws + 268435456);        //  16,777,216
  u16* wqk    = (u16*)(ws + 285212672);        //   1,048,576
  u16* wp     = (u16*)(ws + 286261248);        //   1,048,576
  float* bqk  = (float*)(ws + 287309824);      //       4,096

  k_prep<<<2048, 256, 0, stream>>>(Wq, Wk, bq, bk, Wp, wqk, wp, bqk);
  k_cast<<<16384, 256, 0, stream>>>(state, stB);
  k_qkproj<<<4096, 256, 0, stream>>>(stB, wqk, bqk, qk);
  k_scores<<<dim3(128, 4), 512, 0, stream>>>(qk, mask, wbuf);
  k_mix<<<dim3(128, 4, 8), 256, 0, stream>>>(stB, relation, wbuf, xbuf, relbuf);
  k_proj<<<2048, 256, 0, stream>>>(xbuf, relbuf, wp, bp, yb);
  k_ln<<<2048, 256, 0, stream>>>(yb, stB, gamma, beta, out);
}

// Round 22
// 376.723 us; speedup vs baseline: 1.1020x; 1.0003x over previous
//
#include <hip/hip_runtime.h>

typedef unsigned short u16;
typedef __attribute__((ext_vector_type(4))) unsigned short u16x4;
typedef __attribute__((ext_vector_type(8))) unsigned short u16x8;
typedef __attribute__((ext_vector_type(8))) short bf16x8;
typedef __attribute__((ext_vector_type(4))) float f32x4;

__device__ __forceinline__ u16 f2bf(float f) {
  union { float f; unsigned u; } v; v.f = f;
  unsigned r = v.u + 0x7fffu + ((v.u >> 16) & 1u);
  return (u16)(r >> 16);
}
__device__ __forceinline__ float bf2f(u16 u) {
  union { unsigned u; float f; } v; v.u = ((unsigned)u) << 16;
  return v.f;
}
__device__ __forceinline__ u16x8 pack8(f32x4 a, f32x4 b) {
  u16x8 r = { f2bf(a.x), f2bf(a.y), f2bf(a.z), f2bf(a.w),
              f2bf(b.x), f2bf(b.y), f2bf(b.z), f2bf(b.w) };
  return r;
}
// async global->LDS, 16B per lane; LDS dest = wave-uniform base + lane*16
__device__ __forceinline__ void gload16(const void* g, void* l) {
  __builtin_amdgcn_global_load_lds(
      (const __attribute__((address_space(1))) unsigned int*)g,
      (__attribute__((address_space(3))) unsigned int*)l, 16, 0, 0);
}

// ---------------- K0: weight prep (scale folded into Wq, bq) ----------------
__global__ __launch_bounds__(256) void k_prep(
    const float* __restrict__ Wq, const float* __restrict__ Wk,
    const float* __restrict__ bq, const float* __restrict__ bk,
    const float* __restrict__ Wp,
    u16* __restrict__ wqk, u16* __restrict__ wp, float* __restrict__ bqk) {
  int idx = blockIdx.x * 256 + threadIdx.x;
  if (idx < 524288) {
    int o = idx >> 9, hh = idx & 511;
    wqk[idx] = f2bf((o < 512) ? Wq[o * 512 + hh] * 0.125f : Wk[(o - 512) * 512 + hh]);
    wp[idx] = f2bf(Wp[idx]);
  }
  if (idx < 1024) bqk[idx] = (idx < 512) ? bq[idx] * 0.125f : bk[idx - 512];
}

// ---------------- K-cast: state fp32 -> stB bf16 (flat, one pass) ----------------
__global__ __launch_bounds__(256) void k_cast(
    const float* __restrict__ src, u16* __restrict__ dst) {
  size_t idx = ((size_t)blockIdx.x * 256 + threadIdx.x) * 8;
  f32x4 v0 = *(const f32x4*)&src[idx];
  f32x4 v1 = *(const f32x4*)&src[idx + 4];
  *(u16x8*)&dst[idx] = pack8(v0, v1);
}

// ---------------- K1: q,k projection GEMM (M=65536, N=1024, K=512), bf16 in/out ----------------
// r17 measured-optimum structure. r21 experiment: __launch_bounds__(256,4).
// Occupancy was 26% (2 blocks/CU): VGPR_Count 76 + 64 AGPR acc = ~140 total -> 3 waves/SIMD
// -> only 2 4-wave blocks fit. Cap at 128 total (64 acc + temps) -> 4 waves/SIMD -> 4 blocks/CU.
// Failure signature if it spills: WRITE_SIZE >> 131MB + dur regression (r4 lesson) -> revert.
__global__ __launch_bounds__(256, 4) void k_qkproj(
    const u16* __restrict__ stB, const u16* __restrict__ wqk,
    const float* __restrict__ bqk, u16* __restrict__ qk) {
  const int flat = blockIdx.x;
  const int xcd = flat & 7, local = flat >> 3;          // local 0..511
  const int m0 = (xcd * 64 + (local >> 3)) * 128;       // 512 m-tiles, 64 per XCD
  const int n0 = (local & 7) * 128;                     // 8 n-tiles
  __shared__ u16 smem[17408];  // As[128*64] | Bs[128*64]; epilogue Cs[128][136] overlays
  u16* As = smem;
  u16* Bs = smem + 8192;
  const int tid = threadIdx.x, lane = tid & 63, wid = tid >> 6;
  const int l15 = lane & 15, l4 = lane >> 4;
  const int wm = (wid >> 1) * 64, wn = (wid & 1) * 64;
  const int lr = lane >> 3;                       // staging row-sub 0..7
  const int lcs = ((lane & 7) ^ lr) * 8;          // swizzled source col (u16)
  const int s7 = l15 & 7;                         // read-side row&7
  const f32x4 fz = {0.f, 0.f, 0.f, 0.f};
  f32x4 acc[4][4];
#pragma unroll
  for (int a = 0; a < 4; ++a)
#pragma unroll
    for (int c = 0; c < 4; ++c) acc[a][c] = fz;
  for (int k0 = 0; k0 < 512; k0 += 64) {
    if (k0) __syncthreads();
#pragma unroll
    for (int j = 0; j < 4; ++j) {
      int rb = wid * 32 + j * 8;  // wave-uniform row base
      gload16(&stB[(size_t)(m0 + rb + lr) * 512 + k0 + lcs], &As[rb * 64]);
      gload16(&wqk[(size_t)(n0 + rb + lr) * 512 + k0 + lcs], &Bs[rb * 64]);
    }
    __syncthreads();  // drains vmcnt(0) -> staged data visible
#pragma unroll
    for (int kk = 0; kk < 64; kk += 32) {
      const int cshift = (((kk >> 3) + l4) ^ s7) * 8;  // swizzled read col (u16)
      bf16x8 af[4], bfr[4];
#pragma unroll
      for (int mf = 0; mf < 4; ++mf)
        af[mf] = *(const bf16x8*)&As[(wm + mf * 16 + l15) * 64 + cshift];
#pragma unroll
      for (int nf = 0; nf < 4; ++nf)
        bfr[nf] = *(const bf16x8*)&Bs[(wn + nf * 16 + l15) * 64 + cshift];
#pragma unroll
      for (int mf = 0; mf < 4; ++mf)
#pragma unroll
        for (int nf = 0; nf < 4; ++nf)
          acc[mf][nf] = __builtin_amdgcn_mfma_f32_16x16x32_bf16(af[mf], bfr[nf], acc[mf][nf], 0, 0, 0);
    }
  }
  float bias[4];
#pragma unroll
  for (int nf = 0; nf < 4; ++nf) bias[nf] = bqk[n0 + wn + nf * 16 + l15];
  __syncthreads();
  u16* Cs = smem;  // [128][136]
#pragma unroll
  for (int mf = 0; mf < 4; ++mf)
#pragma unroll
    for (int nf = 0; nf < 4; ++nf)
#pragma unroll
      for (int r = 0; r < 4; ++r)
        Cs[(wm + mf * 16 + l4 * 4 + r) * 136 + wn + nf * 16 + l15] =
            f2bf(acc[mf][nf][r] + bias[nf]);
  __syncthreads();
#pragma unroll
  for (int rr = 0; rr < 8; ++rr) {
    int row = rr * 16 + (tid >> 4), c8 = (tid & 15) * 8;
    *(u16x8*)&qk[(size_t)(m0 + row) * 1024 + n0 + c8] = *(const u16x8*)&Cs[row * 136 + c8];
  }
}

// ---------------- K2: per-(i,b) scores -> softmax -> head-mean -> w (bf16) ----------------
__global__ __launch_bounds__(512) void k_scores(
    const u16* __restrict__ qk, const unsigned char* __restrict__ mask,
    u16* __restrict__ wbuf) {
  const int i = blockIdx.x, b = blockIdx.y;
  __shared__ u16 smem[2 * 128 * 72];
  u16* qs = smem;
  u16* ks = smem + 128 * 72;
  const int tid = threadIdx.x, lane = tid & 63, wid = tid >> 6;  // wid 0..7
  const int l15 = lane & 15, l4 = lane >> 4;
  float wacc[8][4];
#pragma unroll
  for (int nf = 0; nf < 8; ++nf)
#pragma unroll
    for (int r = 0; r < 4; ++r) wacc[nf][r] = 0.f;
  bool mk[8];
#pragma unroll
  for (int nf = 0; nf < 8; ++nf) mk[nf] = mask[i * 512 + b * 128 + nf * 16 + l15] != 0;
  const int arow = tid >> 3, acol = (tid & 7) * 8;  // arow 0..63
  const f32x4 fz = {0.f, 0.f, 0.f, 0.f};
  for (int h = 0; h < 8; ++h) {
    __syncthreads();
#pragma unroll
    for (int rr = 0; rr < 2; ++rr) {
      int row = rr * 64 + arow;
      int base = ((i * 128 + row) * 4 + b) * 1024 + h * 64 + acol;
      *(u16x8*)&qs[row * 72 + acol] = *(const u16x8*)&qk[base];
      *(u16x8*)&ks[row * 72 + acol] = *(const u16x8*)&qk[base + 512];
    }
    __syncthreads();
    f32x4 sc[8];
#pragma unroll
    for (int nf = 0; nf < 8; ++nf) sc[nf] = fz;
#pragma unroll
    for (int kk = 0; kk < 64; kk += 32) {
      bf16x8 a = *(const bf16x8*)&qs[(wid * 16 + l15) * 72 + kk + l4 * 8];
#pragma unroll
      for (int nf = 0; nf < 8; ++nf) {
        bf16x8 bb = *(const bf16x8*)&ks[(nf * 16 + l15) * 72 + kk + l4 * 8];
        sc[nf] = __builtin_amdgcn_mfma_f32_16x16x32_bf16(a, bb, sc[nf], 0, 0, 0);
      }
    }
#pragma unroll
    for (int r = 0; r < 4; ++r) {
      float mx = -3e38f;
#pragma unroll
      for (int nf = 0; nf < 8; ++nf) mx = fmaxf(mx, mk[nf] ? -3e38f : sc[nf][r]);
#pragma unroll
      for (int d = 1; d < 16; d <<= 1) mx = fmaxf(mx, __shfl_xor(mx, d, 64));
      float p[8], sum = 0.f;
#pragma unroll
      for (int nf = 0; nf < 8; ++nf) {
        p[nf] = mk[nf] ? 0.f : __expf(sc[nf][r] - mx);
        sum += p[nf];
      }
#pragma unroll
      for (int d = 1; d < 16; d <<= 1) sum += __shfl_xor(sum, d, 64);
      float inv = 0.125f / sum;
#pragma unroll
      for (int nf = 0; nf < 8; ++nf) wacc[nf][r] += p[nf] * inv;
    }
  }
#pragma unroll
  for (int nf = 0; nf < 8; ++nf)
#pragma unroll
    for (int r = 0; r < 4; ++r) {
      int t = wid * 16 + l4 * 4 + r;
      wbuf[((i * 4 + b) * 128 + t) * 128 + nf * 16 + l15] = f2bf(wacc[nf][r]);
    }
}

// ---------------- K3+K4 merged: x-mix (z<4) and rel-mix (z>=4), transpose fused ----------------
__global__ __launch_bounds__(256) void k_mix(
    const u16* __restrict__ stB, const float* __restrict__ relation,
    const u16* __restrict__ wbuf, u16* __restrict__ xbuf, u16* __restrict__ relbuf) {
  const int q = blockIdx.x, b = blockIdx.y;
  const int hc = blockIdx.z & 3, path = blockIdx.z >> 2;
  __shared__ u16 smem[2 * 128 * 136];
  u16* AT = smem;              // [128][136] A^T[h'][s]
  u16* WS = smem + 128 * 136;  // [128][136] WS[.][s]; T scratch overlays this
  u16* T = WS;                 // [32][136]
  const int tid = threadIdx.x, lane = tid & 63, wid = tid >> 6;
  const int l15 = lane & 15, l4 = lane >> 4;
  const int wh = (wid >> 1) * 64, wc = (wid & 1) * 64;
  const int sr = tid >> 3, hseg = (tid & 7) * 16;  // chunk-load (32 s-rows x 128 h)
  const int th = tid >> 1, sseg = (tid & 1) * 16;  // scatter (128 h x 32 s)
#pragma unroll
  for (int ch = 0; ch < 4; ++ch) {
    const int sbase = ch * 32;
    u16x8 r0, r1;
    if (path == 0) {
      size_t gaddr = ((size_t)(q * 128 + sbase + sr) * 4 + b) * 512 + hc * 128 + hseg;
      r0 = *(const u16x8*)&stB[gaddr];
      r1 = *(const u16x8*)&stB[gaddr + 8];
    } else {
      size_t gaddr = (((size_t)(sbase + sr) * 128 + q) * 4 + b) * 512 + hc * 128 + hseg;
      f32x4 v0 = *(const f32x4*)&relation[gaddr];
      f32x4 v1 = *(const f32x4*)&relation[gaddr + 4];
      f32x4 v2 = *(const f32x4*)&relation[gaddr + 8];
      f32x4 v3 = *(const f32x4*)&relation[gaddr + 12];
      r0 = pack8(v0, v1);
      r1 = pack8(v2, v3);
    }
    __syncthreads();  // previous chunk's T readers done
    *(u16x8*)&T[sr * 136 + hseg] = r0;
    *(u16x8*)&T[sr * 136 + hseg + 8] = r1;
    __syncthreads();
    u16x8 c0, c1;
#pragma unroll
    for (int j = 0; j < 8; ++j) c0[j] = T[(sseg + j) * 136 + th];
#pragma unroll
    for (int j = 0; j < 8; ++j) c1[j] = T[(sseg + 8 + j) * 136 + th];
    *(u16x8*)&AT[th * 136 + sbase + sseg] = c0;
    *(u16x8*)&AT[th * 136 + sbase + sseg + 8] = c1;
  }
  __syncthreads();  // last chunk's T readers done before WS fill overwrites T
  const int r16 = tid >> 4, c8 = (tid & 15) * 8;
#pragma unroll
  for (int rr = 0; rr < 8; ++rr) {
    int row = rr * 16 + r16;
    const u16* src = (path == 0) ? &wbuf[((q * 4 + b) * 128 + row) * 128 + c8]
                                 : &wbuf[((row * 4 + b) * 128 + q) * 128 + c8];
    *(u16x8*)&WS[row * 136 + c8] = *(const u16x8*)src;
  }
  __syncthreads();
  const f32x4 fz = {0.f, 0.f, 0.f, 0.f};
  f32x4 acc[4][4];
#pragma unroll
  for (int a = 0; a < 4; ++a)
#pragma unroll
    for (int c = 0; c < 4; ++c) acc[a][c] = fz;
#pragma unroll
  for (int kk = 0; kk < 128; kk += 32) {
    bf16x8 af[4], bfr[4];
#pragma unroll
    for (int mf = 0; mf < 4; ++mf)
      af[mf] = *(const bf16x8*)&AT[(wh + mf * 16 + l15) * 136 + kk + l4 * 8];
#pragma unroll
    for (int nf = 0; nf < 4; ++nf)
      bfr[nf] = *(const bf16x8*)&WS[(wc + nf * 16 + l15) * 136 + kk + l4 * 8];
#pragma unroll
    for (int mf = 0; mf < 4; ++mf)
#pragma unroll
      for (int nf = 0; nf < 4; ++nf)
        acc[mf][nf] = __builtin_amdgcn_mfma_f32_16x16x32_bf16(af[mf], bfr[nf], acc[mf][nf], 0, 0, 0);
  }
  __syncthreads();
  u16* Cs = smem;  // [out][h] 128x136
#pragma unroll
  for (int mf = 0; mf < 4; ++mf)
#pragma unroll
    for (int nf = 0; nf < 4; ++nf) {
      int h0 = wh + mf * 16 + l4 * 4;
      int oc = wc + nf * 16 + l15;
      u16x4 pk = { f2bf(acc[mf][nf][0]), f2bf(acc[mf][nf][1]),
                   f2bf(acc[mf][nf][2]), f2bf(acc[mf][nf][3]) };
      *(u16x4*)&Cs[oc * 136 + h0] = pk;
    }
  __syncthreads();
#pragma unroll
  for (int rr = 0; rr < 8; ++rr) {
    int o = rr * 16 + r16;
    u16x8 v = *(const u16x8*)&Cs[o * 136 + c8];
    if (path == 0)
      *(u16x8*)&xbuf[((q * 128 + o) * 4 + b) * 512 + hc * 128 + c8] = v;
    else
      *(u16x8*)&relbuf[((o * 128 + q) * 4 + b) * 512 + hc * 128 + c8] = v;
  }
}

// ---------------- K5a: out-proj GEMM (M=65536,N=512,K=1024) + bias + relu -> yb bf16 ----------------
// 2-barrier form + launch_bounds(256,4) occupancy experiment (see k_qkproj).
__global__ __launch_bounds__(256, 4) void k_proj(
    const u16* __restrict__ xbuf, const u16* __restrict__ relbuf,
    const u16* __restrict__ wp, const float* __restrict__ bp,
    u16* __restrict__ yb) {
  const int flat = blockIdx.x;
  const int xcd = flat & 7, local = flat >> 3;          // local 0..255
  const int m0 = (xcd * 64 + (local >> 2)) * 128;
  const int n0 = (local & 3) * 128;
  __shared__ u16 smem[17408];
  u16* As = smem;
  u16* Bs = smem + 8192;
  const int tid = threadIdx.x, lane = tid & 63, wid = tid >> 6;
  const int l15 = lane & 15, l4 = lane >> 4;
  const int wm = (wid >> 1) * 64, wn = (wid & 1) * 64;
  const int lr = lane >> 3;
  const int lcs = ((lane & 7) ^ lr) * 8;
  const int s7 = l15 & 7;
  const f32x4 fz = {0.f, 0.f, 0.f, 0.f};
  f32x4 acc[4][4];
#pragma unroll
  for (int a = 0; a < 4; ++a)
#pragma unroll
    for (int c = 0; c < 4; ++c) acc[a][c] = fz;
  for (int k0 = 0; k0 < 1024; k0 += 64) {
    if (k0) __syncthreads();
    const u16* abase = (k0 < 512) ? xbuf + k0 : relbuf + (k0 - 512);
#pragma unroll
    for (int j = 0; j < 4; ++j) {
      int rb = wid * 32 + j * 8;
      gload16(&abase[(size_t)(m0 + rb + lr) * 512 + lcs], &As[rb * 64]);
      gload16(&wp[(size_t)(n0 + rb + lr) * 1024 + k0 + lcs], &Bs[rb * 64]);
    }
    __syncthreads();
#pragma unroll
    for (int kk = 0; kk < 64; kk += 32) {
      const int cshift = (((kk >> 3) + l4) ^ s7) * 8;
      bf16x8 af[4], bfr[4];
#pragma unroll
      for (int mf = 0; mf < 4; ++mf)
        af[mf] = *(const bf16x8*)&As[(wm + mf * 16 + l15) * 64 + cshift];
#pragma unroll
      for (int nf = 0; nf < 4; ++nf)
        bfr[nf] = *(const bf16x8*)&Bs[(wn + nf * 16 + l15) * 64 + cshift];
#pragma unroll
      for (int mf = 0; mf < 4; ++mf)
#pragma unroll
        for (int nf = 0; nf < 4; ++nf)
          acc[mf][nf] = __builtin_amdgcn_mfma_f32_16x16x32_bf16(af[mf], bfr[nf], acc[mf][nf], 0, 0, 0);
    }
  }
  float bias[4];
#pragma unroll
  for (int nf = 0; nf < 4; ++nf) bias[nf] = bp[n0 + wn + nf * 16 + l15];
  __syncthreads();
  u16* Cs = smem;  // [128][136]
#pragma unroll
  for (int mf = 0; mf < 4; ++mf)
#pragma unroll
    for (int nf = 0; nf < 4; ++nf)
#pragma unroll
      for (int r = 0; r < 4; ++r)
        Cs[(wm + mf * 16 + l4 * 4 + r) * 136 + wn + nf * 16 + l15] =
            f2bf(fmaxf(acc[mf][nf][r] + bias[nf], 0.f));
  __syncthreads();
#pragma unroll
  for (int rr = 0; rr < 8; ++rr) {
    int row = rr * 16 + (tid >> 4), c8 = (tid & 15) * 8;
    *(u16x8*)&yb[(size_t)(m0 + row) * 512 + n0 + c8] = *(const u16x8*)&Cs[row * 136 + c8];
  }
}

// ---------------- K5b: residual + LayerNorm (memory-bound row pass) ----------------
__global__ __launch_bounds__(256) void k_ln(
    const u16* __restrict__ yb, const u16* __restrict__ stB,
    const float* __restrict__ gamma, const float* __restrict__ beta,
    float* __restrict__ out) {
  const int tid = threadIdx.x, lane = tid & 63, wid = tid >> 6;
  f32x4 g0 = *(const f32x4*)&gamma[lane * 8];
  f32x4 g1 = *(const f32x4*)&gamma[lane * 8 + 4];
  f32x4 be0 = *(const f32x4*)&beta[lane * 8];
  f32x4 be1 = *(const f32x4*)&beta[lane * 8 + 4];
  for (int row = blockIdx.x * 4 + wid; row < 65536; row += gridDim.x * 4) {
    size_t gbase = (size_t)row * 512 + lane * 8;
    u16x8 yv = *(const u16x8*)&yb[gbase];
    u16x8 sv = *(const u16x8*)&stB[gbase];
    float y[8];
#pragma unroll
    for (int j = 0; j < 8; ++j) y[j] = bf2f(yv[j]) + bf2f(sv[j]);
    float sum = 0.f, sq = 0.f;
#pragma unroll
    for (int j = 0; j < 8; ++j) { sum += y[j]; sq += y[j] * y[j]; }
#pragma unroll
    for (int d = 1; d < 64; d <<= 1) { sum += __shfl_xor(sum, d, 64); sq += __shfl_xor(sq, d, 64); }
    float mu = sum * (1.f / 512.f);
    float var = sq * (1.f / 512.f) - mu * mu;
    float rs = rsqrtf(var + 1e-5f);
    f32x4 o0, o1;
#pragma unroll
    for (int j = 0; j < 4; ++j) o0[j] = g0[j] * (y[j] - mu) * rs + be0[j];
#pragma unroll
    for (int j = 0; j < 4; ++j) o1[j] = g1[j] * (y[4 + j] - mu) * rs + be1[j];
    *(f32x4*)&out[gbase] = o0;
    *(f32x4*)&out[gbase + 4] = o1;
  }
}

extern "C" void kernel_launch(void* const* d_in, const int* in_sizes, int n_in,
                              void* d_out, int out_size, void* d_ws, size_t ws_size,
                              hipStream_t stream) {
  const float* state = (const float*)d_in[0];
  const float* relation = (const float*)d_in[1];
  const unsigned char* mask = (const unsigned char*)d_in[2];
  const float* Wq = (const float*)d_in[4];
  const float* bq = (const float*)d_in[5];
  const float* Wk = (const float*)d_in[6];
  const float* bk = (const float*)d_in[7];
  const float* Wp = (const float*)d_in[8];
  const float* bp = (const float*)d_in[9];
  const float* gamma = (const float*)d_in[10];
  const float* beta = (const float*)d_in[11];
  float* out = (float*)d_out;
  char* ws = (char*)d_ws;

  // workspace layout (bytes); aliases (lifetimes disjoint):
  //   xbuf/relbuf alias qk (dead after k_scores)
  //   stB read by k_qkproj, k_mix, k_ln — nothing overwrites its region
  u16* qk     = (u16*)(ws);                    // 134,217,728
  u16* xbuf   = (u16*)(ws);                    //  67,108,864 (alias qk lower half)
  u16* relbuf = (u16*)(ws + 67108864);         //  67,108,864 (alias qk upper half)
  u16* yb     = (u16*)(ws + 134217728);        //  67,108,864
  u16* stB    = (u16*)(ws + 201326592);        //  67,108,864
  u16* wbuf   = (u16*)(ws + 268435456);        //  16,777,216
  u16* wqk    = (u16*)(ws + 285212672);        //   1,048,576
  u16* wp     = (u16*)(ws + 286261248);        //   1,048,576
  float* bqk  = (float*)(ws + 287309824);      //       4,096

  k_prep<<<2048, 256, 0, stream>>>(Wq, Wk, bq, bk, Wp, wqk, wp, bqk);
  k_cast<<<16384, 256, 0, stream>>>(state, stB);
  k_qkproj<<<4096, 256, 0, stream>>>(stB, wqk, bqk, qk);
  k_scores<<<dim3(128, 4), 512, 0, stream>>>(qk, mask, wbuf);
  k_mix<<<dim3(128, 4, 8), 256, 0, stream>>>(stB, relation, wbuf, xbuf, relbuf);
  k_proj<<<2048, 256, 0, stream>>>(xbuf, relbuf, wp, bp, yb);
  k_ln<<<2048, 256, 0, stream>>>(yb, stB, gamma, beta, out);
}